// Round 2
// 732.758 us; speedup vs baseline: 1.0223x; 1.0223x over previous
//
#include <hip/hip_runtime.h>
#include <math.h>

// Problem constants (match reference)
#define INVALID_TOKEN_ID (-1)
constexpr int BB = 128;          // batch
constexpr int KK = 8;            // spec length
constexpr int VV = 128000;       // vocab
constexpr int ROWS = BB * (KK + 1);   // 1152 rows of target_probs
constexpr int THREADS = 256;

// Row-splitting for balance + occupancy:
// 5 blocks/row -> 5760 blocks = 22.5/CU (fine-grained, 8 resident = 32 waves/CU)
constexpr int SPLIT   = 5;
constexpr int NPART   = ROWS * SPLIT;        // 5760 u64 partials (46 KB of ws)
constexpr int CHUNK4  = (VV / 4) / SPLIT;    // 6400 float4 per block
constexpr int ITERS   = CHUNK4 / THREADS;    // 25 iterations/thread (exact)
constexpr int BATCH   = 5;                   // loads in flight per buffer
constexpr int NBATCH  = ITERS / BATCH;       // 5 (exact)

// Native vector type for clean dwordx4 codegen.
typedef float f32x4 __attribute__((ext_vector_type(4)));

// Pack (value, index) into one u64 so all reductions are a single u64 max.
//   high 32: float bits (probs in [0,1) -> non-negative -> bit-pattern is
//            order-preserving as unsigned)
//   low  32: ~idx  (equal values -> larger ~idx wins -> SMALLER index wins,
//            matching jnp.argmax first-occurrence tie-break; ties at the row
//            max genuinely occur with 24-bit-mantissa uniforms)
__device__ __forceinline__ unsigned long long pack_vi(float v, int idx) {
    return ((unsigned long long)__float_as_uint(v) << 32) |
           (unsigned int)(~idx);
}

// Kernel 1: per-(row,segment) argmax partial.
// Compile-time trip counts, double-buffered register pipeline (5-10
// dwordx4 outstanding/wave), max-tree compare so the loop-carried chain is
// one fmaxf + one cmp. All buffer indices are compile-time (rule: runtime-
// indexed vector arrays spill to scratch).
__global__ __launch_bounds__(THREADS) void argmax_part_kernel(
    const float* __restrict__ probs, unsigned long long* __restrict__ part) {
    const int bid = blockIdx.x;
    const int row = bid / SPLIT;
    const int seg = bid % SPLIT;
    const int tid = threadIdx.x;

    const f32x4* __restrict__ p4 =
        (const f32x4*)(probs + (size_t)row * VV) + seg * CHUNK4;

    float best = -1.0f;      // replaced by first quad (all values >= 0)
    int bestIdx = 0;

    f32x4 cur[BATCH], nxt[BATCH];

    #pragma unroll
    for (int u = 0; u < BATCH; ++u)
        cur[u] = p4[tid + u * THREADS];

    #pragma unroll
    for (int g = 0; g < NBATCH; ++g) {
        // Issue next batch before consuming current: keeps ~2*BATCH loads
        // in flight across the vmcnt wait on cur[].
        if (g + 1 < NBATCH) {
            #pragma unroll
            for (int u = 0; u < BATCH; ++u)
                nxt[u] = p4[tid + ((g + 1) * BATCH + u) * THREADS];
        }
        #pragma unroll
        for (int u = 0; u < BATCH; ++u) {
            f32x4 v = cur[u];
            float m = fmaxf(fmaxf(v[0], v[1]), fmaxf(v[2], v[3]));
            if (m > best) {   // strict '>': earlier quads win ties (indices
                              // increase monotonically within a thread)
                int q    = tid + (g * BATCH + u) * THREADS; // quad idx in seg
                int base = (seg * CHUNK4 + q) * 4;          // float idx in row
                best = m;
                // first element of the quad equal to its max -> first occurrence
                bestIdx = (v[0] == m) ? base
                        : (v[1] == m) ? base + 1
                        : (v[2] == m) ? base + 2
                        :               base + 3;
            }
        }
        if (g + 1 < NBATCH) {
            #pragma unroll
            for (int u = 0; u < BATCH; ++u) cur[u] = nxt[u];
        }
    }

    // Single-u64 lexicographic reduction (value desc, index asc).
    unsigned long long packed = pack_vi(best, bestIdx);

    #pragma unroll
    for (int off = 32; off > 0; off >>= 1) {
        unsigned long long o = __shfl_down(packed, off, 64);
        packed = (o > packed) ? o : packed;
    }

    __shared__ unsigned long long s_p[THREADS / 64];
    const int wave = tid >> 6;
    const int lane = tid & 63;
    if (lane == 0) s_p[wave] = packed;
    __syncthreads();
    if (tid == 0) {
        #pragma unroll
        for (int w = 1; w < THREADS / 64; ++w)
            packed = (s_p[w] > packed) ? s_p[w] : packed;
        part[bid] = packed;
    }
}

// Kernel 2: reduce SPLIT partials per row + accept-mask logic, fused.
// One thread per batch element; 45 u64 reads/thread from L2/L3 (46 KB total).
__global__ __launch_bounds__(128) void reduce_finalize_kernel(
    const unsigned long long* __restrict__ part,
    const int* __restrict__ draft, int* __restrict__ out) {
    const int b = threadIdx.x;
    if (b >= BB) return;

    int toks[KK + 1];
    #pragma unroll
    for (int j = 0; j <= KK; ++j) {
        const unsigned long long* pr = part + (size_t)(b * (KK + 1) + j) * SPLIT;
        unsigned long long m = pr[0];
        #pragma unroll
        for (int s = 1; s < SPLIT; ++s)
            m = (pr[s] > m) ? pr[s] : m;
        toks[j] = (int)(~(unsigned int)(m & 0xFFFFFFFFull));  // recover index
    }

    const int* drow = draft + b * KK;
    int r = 0;
    while (r < KK && toks[r] == drow[r]) ++r;

    int* orow = out + b * (KK + 1);
    #pragma unroll
    for (int j = 0; j <= KK; ++j)
        orow[j] = (j <= r) ? toks[j] : INVALID_TOKEN_ID;
}

extern "C" void kernel_launch(void* const* d_in, const int* in_sizes, int n_in,
                              void* d_out, int out_size, void* d_ws, size_t ws_size,
                              hipStream_t stream) {
    const int*   draft = (const int*)d_in[0];     // [B, K] int32
    const float* probs = (const float*)d_in[1];   // [B*(K+1), V] fp32
    int* out = (int*)d_out;                       // [B, K+1] int32
    unsigned long long* part = (unsigned long long*)d_ws;  // 5760 u64 scratch

    argmax_part_kernel<<<NPART, THREADS, 0, stream>>>(probs, part);
    reduce_finalize_kernel<<<1, 128, 0, stream>>>(part, draft, out);
}

// Round 3
// 697.815 us; speedup vs baseline: 1.0735x; 1.0501x over previous
//
#include <hip/hip_runtime.h>
#include <math.h>

// Problem constants (match reference)
#define INVALID_TOKEN_ID (-1)
constexpr int BB = 128;          // batch
constexpr int KK = 8;            // spec length
constexpr int VV = 128000;       // vocab
constexpr int ROWS = BB * (KK + 1);   // 1152 rows of target_probs
constexpr int THREADS = 256;

// Row-splitting for balance + occupancy:
// 5 blocks/row -> 5760 blocks = 22.5/CU (fine-grained, 8 resident = 32 waves/CU)
constexpr int SPLIT   = 5;
constexpr int NPART   = ROWS * SPLIT;        // 5760 u64 partials (46 KB of ws)
constexpr int CHUNK4  = (VV / 4) / SPLIT;    // 6400 float4 per block
constexpr int ITERS   = CHUNK4 / THREADS;    // 25 iterations/thread (exact)
constexpr int BATCH   = 5;                   // loads in flight per buffer
constexpr int NBATCH  = ITERS / BATCH;       // 5 (exact)

// Native vector type for clean dwordx4 codegen.
typedef float f32x4 __attribute__((ext_vector_type(4)));

// Pack (value, index) into one u64 so all reductions are a single u64 max.
//   high 32: float bits (probs in [0,1) -> non-negative -> bit-pattern is
//            order-preserving as unsigned)
//   low  32: ~idx  (equal values -> larger ~idx wins -> SMALLER index wins,
//            matching jnp.argmax first-occurrence tie-break; ties at the row
//            max genuinely occur with 24-bit-mantissa uniforms)
__device__ __forceinline__ unsigned long long pack_vi(float v, int idx) {
    return ((unsigned long long)__float_as_uint(v) << 32) |
           (unsigned int)(~idx);
}

// Kernel 1: per-(row,segment) argmax partial.
// SINGLE-VARIABLE CHANGE vs round 2: probs loads are NONTEMPORAL
// (stream-once data; skip L1/L2 allocate -> no read-allocate/writeback
// serialization against the 2.36 GB dirty poison fill that precedes us).
__global__ __launch_bounds__(THREADS) void argmax_part_kernel(
    const float* __restrict__ probs, unsigned long long* __restrict__ part) {
    const int bid = blockIdx.x;
    const int row = bid / SPLIT;
    const int seg = bid % SPLIT;
    const int tid = threadIdx.x;

    const f32x4* __restrict__ p4 =
        (const f32x4*)(probs + (size_t)row * VV) + seg * CHUNK4;

    float best = -1.0f;      // replaced by first quad (all values >= 0)
    int bestIdx = 0;

    f32x4 cur[BATCH], nxt[BATCH];

    #pragma unroll
    for (int u = 0; u < BATCH; ++u)
        cur[u] = __builtin_nontemporal_load(p4 + tid + u * THREADS);

    #pragma unroll
    for (int g = 0; g < NBATCH; ++g) {
        // Issue next batch before consuming current: keeps ~2*BATCH loads
        // in flight across the vmcnt wait on cur[].
        if (g + 1 < NBATCH) {
            #pragma unroll
            for (int u = 0; u < BATCH; ++u)
                nxt[u] = __builtin_nontemporal_load(
                    p4 + tid + ((g + 1) * BATCH + u) * THREADS);
        }
        #pragma unroll
        for (int u = 0; u < BATCH; ++u) {
            f32x4 v = cur[u];
            float m = fmaxf(fmaxf(v[0], v[1]), fmaxf(v[2], v[3]));
            if (m > best) {   // strict '>': earlier quads win ties (indices
                              // increase monotonically within a thread)
                int q    = tid + (g * BATCH + u) * THREADS; // quad idx in seg
                int base = (seg * CHUNK4 + q) * 4;          // float idx in row
                best = m;
                // first element of the quad equal to its max -> first occurrence
                bestIdx = (v[0] == m) ? base
                        : (v[1] == m) ? base + 1
                        : (v[2] == m) ? base + 2
                        :               base + 3;
            }
        }
        if (g + 1 < NBATCH) {
            #pragma unroll
            for (int u = 0; u < BATCH; ++u) cur[u] = nxt[u];
        }
    }

    // Single-u64 lexicographic reduction (value desc, index asc).
    unsigned long long packed = pack_vi(best, bestIdx);

    #pragma unroll
    for (int off = 32; off > 0; off >>= 1) {
        unsigned long long o = __shfl_down(packed, off, 64);
        packed = (o > packed) ? o : packed;
    }

    __shared__ unsigned long long s_p[THREADS / 64];
    const int wave = tid >> 6;
    const int lane = tid & 63;
    if (lane == 0) s_p[wave] = packed;
    __syncthreads();
    if (tid == 0) {
        #pragma unroll
        for (int w = 1; w < THREADS / 64; ++w)
            packed = (s_p[w] > packed) ? s_p[w] : packed;
        part[bid] = packed;
    }
}

// Kernel 2: reduce SPLIT partials per row + accept-mask logic, fused.
// One thread per batch element; 45 u64 reads/thread from L2/L3 (46 KB total).
// Partials/draft stay on the cached path (they are hot, just-written data).
__global__ __launch_bounds__(128) void reduce_finalize_kernel(
    const unsigned long long* __restrict__ part,
    const int* __restrict__ draft, int* __restrict__ out) {
    const int b = threadIdx.x;
    if (b >= BB) return;

    int toks[KK + 1];
    #pragma unroll
    for (int j = 0; j <= KK; ++j) {
        const unsigned long long* pr = part + (size_t)(b * (KK + 1) + j) * SPLIT;
        unsigned long long m = pr[0];
        #pragma unroll
        for (int s = 1; s < SPLIT; ++s)
            m = (pr[s] > m) ? pr[s] : m;
        toks[j] = (int)(~(unsigned int)(m & 0xFFFFFFFFull));  // recover index
    }

    const int* drow = draft + b * KK;
    int r = 0;
    while (r < KK && toks[r] == drow[r]) ++r;

    int* orow = out + b * (KK + 1);
    #pragma unroll
    for (int j = 0; j <= KK; ++j)
        orow[j] = (j <= r) ? toks[j] : INVALID_TOKEN_ID;
}

extern "C" void kernel_launch(void* const* d_in, const int* in_sizes, int n_in,
                              void* d_out, int out_size, void* d_ws, size_t ws_size,
                              hipStream_t stream) {
    const int*   draft = (const int*)d_in[0];     // [B, K] int32
    const float* probs = (const float*)d_in[1];   // [B*(K+1), V] fp32
    int* out = (int*)d_out;                       // [B, K+1] int32
    unsigned long long* part = (unsigned long long*)d_ws;  // 5760 u64 scratch

    argmax_part_kernel<<<NPART, THREADS, 0, stream>>>(probs, part);
    reduce_finalize_kernel<<<1, 128, 0, stream>>>(part, draft, out);
}